// Round 4
// baseline (240.164 us; speedup 1.0000x reference)
//
#include <hip/hip_runtime.h>

// ---------------- types / helpers ----------------
typedef __attribute__((ext_vector_type(8))) short bf16x8;   // 8 bf16 = 4 VGPR
typedef __attribute__((ext_vector_type(4))) float f32x4;
typedef __attribute__((ext_vector_type(16))) float f32x16;
typedef int v2i __attribute__((ext_vector_type(2)));

union U4B { unsigned u[4]; bf16x8 v; };

__device__ __forceinline__ unsigned short f2bf(float f) {
    union { float f; unsigned u; } v; v.f = f;
    unsigned r = v.u + 0x7fffu + ((v.u >> 16) & 1u);   // RNE
    return (unsigned short)(r >> 16);
}
__device__ __forceinline__ float bf2f(unsigned short s) {
    union { unsigned u; float f; } v; v.u = ((unsigned)s) << 16; return v.f;
}
__device__ __forceinline__ unsigned pkbf(float a, float b) {
    unsigned r;
    asm("v_cvt_pk_bf16_f32 %0, %1, %2" : "=v"(r) : "v"(a), "v"(b));
    return r;
}
// C-frag half (regs base..base+7) -> B-frag of the next layer (verified r3)
__device__ __forceinline__ bf16x8 packhalf(const f32x16& a, int base) {
    unsigned u  = pkbf(a[base + 0], a[base + 1]);
    unsigned u2 = pkbf(a[base + 2], a[base + 3]);
    unsigned v  = pkbf(a[base + 4], a[base + 5]);
    unsigned v2 = pkbf(a[base + 6], a[base + 7]);
    v2i r1 = __builtin_amdgcn_permlane32_swap(u, v, false, false);
    v2i r2 = __builtin_amdgcn_permlane32_swap(u2, v2, false, false);
    U4B b; b.u[0] = r1.x; b.u[1] = r2.x; b.u[2] = r1.y; b.u[3] = r2.y;
    return b.v;
}
__device__ __forceinline__ f32x16 zero16() {
    f32x16 v;
#pragma unroll
    for (int i = 0; i < 16; ++i) v[i] = 0.f;
    return v;
}

// ---------------- problem constants ----------------
#define BATCH   2048
#define TSTEPS  300
#define ROWS_PB 8            // batch rows per main block (16 waves)
// workspace layout (bytes)
#define WM_OFF  0            // 3 * 128*128 bf16 main weights (bias@k=100, carrier n=100)
#define G_OFF   98304        // 2048*128 bf16
#define E_OFF   622592       // 2048*128 bf16  (ends 1146880)
// main-kernel LDS (bytes)
#define OFF_X   98304        // 8*128 f32
#define OFF_G   102400
#define OFF_E   106496
#define OFF_P   110592       // 16 f32 wave partials
#define SMEM_M  110656
// embed-kernel LDS (bytes): staging area 0..114688, biases after
#define EB1     114688       // 224 f32
#define EB2     115584       // 224 f32
#define EB3     116480       // 64 f32
#define EC1     116736       // 128 f32
#define SMEM_E  117248

// ---------------- prep: main-path weights only (carrier scheme) ----------------
__global__ __launch_bounds__(256) void prep_kernel(
    const float* __restrict__ U2, const float* __restrict__ c2,
    const float* __restrict__ U3, const float* __restrict__ c3,
    const float* __restrict__ U4, const float* __restrict__ c4,
    unsigned char* __restrict__ ws)
{
    int idx = blockIdx.x * 256 + threadIdx.x;          // grid = 24 blocks
    for (int i = idx; i < 3 * 128 * 128; i += 24 * 256) {
        int m = i >> 14;
        int r = i & 16383;
        int n = r >> 7;           // out-neuron (row)
        int k = r & 127;          // in-neuron
        float v = 0.f;
        if (m == 2) {             // U4: (k=100 in) x (n=128 out)
            if (k < 100)       v = U4[k * 128 + n];
            else if (k == 100) v = c4[n];
        } else {                  // U2 / U3: 100x100
            const float* U = (m == 0) ? U2 : U3;
            const float* c = (m == 0) ? c2 : c3;
            if (n < 100) {
                if (k < 100)       v = U[k * 100 + n];
                else if (k == 100) v = c[n];
            } else if (n == 100 && k == 100) {
                v = 1.f;          // identity pass-through of the bias-carrier 1
            }
        }
        *(unsigned short*)(ws + WM_OFF + m * 32768 + n * 256 + k * 2) = f2bf(v);
    }
}

// ---------------- embed: MFMA pipeline, wave = 32 batch rows ----------------
// B-frag: col = batch row (lane&31), k = 16ks+8hi+j. A-frag: weight rows
// n = 32f+l31 from swizzled LDS. Repack between layers via packhalf.
// Outputs (bf16): g = x@U1x, e = h@U1h + c1, e[100]=1 (carrier for main).
__global__ __launch_bounds__(256, 1) void embed2(
    const float* __restrict__ x,
    const float* __restrict__ W1, const float* __restrict__ b1,
    const float* __restrict__ W2, const float* __restrict__ b2,
    const float* __restrict__ W3, const float* __restrict__ b3,
    const float* __restrict__ U1, const float* __restrict__ c1,
    unsigned char* __restrict__ ws)
{
    extern __shared__ char sm[];
    const int tid = threadIdx.x;
    const int lane = tid & 63, wid = tid >> 6;
    const int l31 = lane & 31, hi = lane >> 5;
    const int brow = blockIdx.x * 128 + wid * 32 + l31;   // grid = 16
    const int sw8 = (l31 & 15) << 4;    // 256B-row swizzle
    const int sw9 = (l31 & 31) << 4;    // 512B-row swizzle

    // biases -> LDS
    for (int i = tid; i < 224; i += 256) ((float*)(sm + EB1))[i] = (i < 200) ? b1[i] : 0.f;
    for (int i = tid; i < 224; i += 256) ((float*)(sm + EB2))[i] = (i < 200) ? b2[i] : 0.f;
    if (tid < 64)  ((float*)(sm + EB3))[tid] = b3[tid];
    if (tid < 128) ((float*)(sm + EC1))[tid] = (tid < 100) ? c1[tid] : 0.f;

    // ---- phase A: stage W1' [224][128] and U1x [128][128] (bf16, swizzled)
    for (int i = tid; i < 224 * 128; i += 256) {
        int n = i >> 7, k = i & 127;
        float v = (n < 200) ? W1[k * 200 + n] : 0.f;
        *(unsigned short*)(sm + n * 256 + ((k * 2) ^ ((n & 15) << 4))) = f2bf(v);
    }
    for (int i = tid; i < 128 * 128; i += 256) {
        int n = i >> 7, k = i & 127;
        float v = (n < 100) ? U1[k * 100 + n] : 0.f;
        *(unsigned short*)(sm + 57344 + n * 256 + ((k * 2) ^ ((n & 15) << 4))) = f2bf(v);
    }
    __syncthreads();

    // x B-frags (32 rows per wave)
    bf16x8 Bx[8];
    {
        const float* xr = x + brow * 128;
#pragma unroll
        for (int ks = 0; ks < 8; ++ks) {
            const int k0 = ks * 16 + hi * 8;
            f32x4 a = *(const f32x4*)(xr + k0);
            f32x4 b = *(const f32x4*)(xr + k0 + 4);
            U4B u;
            u.u[0] = pkbf(a[0], a[1]); u.u[1] = pkbf(a[2], a[3]);
            u.u[2] = pkbf(b[0], b[1]); u.u[3] = pkbf(b[2], b[3]);
            Bx[ks] = u.v;
        }
    }

    unsigned short* g16 = (unsigned short*)(ws + G_OFF);
    unsigned short* e16 = (unsigned short*)(ws + E_OFF);

    // ---- g = x @ U1x  (no bias, no relu)
    {
        f32x16 ag[4];
#pragma unroll
        for (int f = 0; f < 4; ++f) ag[f] = zero16();
#pragma unroll
        for (int ks = 0; ks < 8; ++ks)
#pragma unroll
            for (int f = 0; f < 4; ++f) {
                bf16x8 a = *(const bf16x8*)(sm + 57344 + (32 * f + l31) * 256 + ((ks * 32 + hi * 16) ^ sw8));
                ag[f] = __builtin_amdgcn_mfma_f32_32x32x16_bf16(a, Bx[ks], ag[f], 0, 0, 0);
            }
#pragma unroll
        for (int f = 0; f < 4; ++f)
#pragma unroll
            for (int r = 0; r < 16; r += 2) {
                int n = 32 * f + (r & 3) + 8 * (r >> 2) + 4 * hi;
                *(unsigned*)(g16 + brow * 128 + n) = pkbf(ag[f][r], ag[f][r + 1]);
            }
    }

    // ---- layer 1: h1 = relu(x@W1 + b1) -> Bh[13] (K=208)
    bf16x8 Bh[13];
    {
        f32x16 acc[7];
#pragma unroll
        for (int f = 0; f < 7; ++f)
#pragma unroll
            for (int r = 0; r < 16; ++r)
                acc[f][r] = ((float*)(sm + EB1))[32 * f + (r & 3) + 8 * (r >> 2) + 4 * hi];
#pragma unroll
        for (int ks = 0; ks < 8; ++ks)
#pragma unroll
            for (int f = 0; f < 7; ++f) {
                bf16x8 a = *(const bf16x8*)(sm + (32 * f + l31) * 256 + ((ks * 32 + hi * 16) ^ sw8));
                acc[f] = __builtin_amdgcn_mfma_f32_32x32x16_bf16(a, Bx[ks], acc[f], 0, 0, 0);
            }
#pragma unroll
        for (int f = 0; f < 7; ++f) {
#pragma unroll
            for (int r = 0; r < 16; ++r) acc[f][r] = fmaxf(acc[f][r], 0.f);
            Bh[2 * f] = packhalf(acc[f], 0);
            if (f < 6) Bh[2 * f + 1] = packhalf(acc[f], 8);
        }
    }
    __syncthreads();

    // ---- phase B: stage W2' [224][256]
    for (int i = tid; i < 224 * 256; i += 256) {
        int n = i >> 8, k = i & 255;
        float v = (n < 200 && k < 200) ? W2[k * 200 + n] : 0.f;
        *(unsigned short*)(sm + n * 512 + ((k * 2) ^ ((n & 31) << 4))) = f2bf(v);
    }
    __syncthreads();

    // ---- layer 2: h2 = relu(h1@W2 + b2) -> Bh2[13]
    bf16x8 Bh2[13];
    {
        f32x16 acc[7];
#pragma unroll
        for (int f = 0; f < 7; ++f)
#pragma unroll
            for (int r = 0; r < 16; ++r)
                acc[f][r] = ((float*)(sm + EB2))[32 * f + (r & 3) + 8 * (r >> 2) + 4 * hi];
#pragma unroll
        for (int ks = 0; ks < 13; ++ks)
#pragma unroll
            for (int f = 0; f < 7; ++f) {
                bf16x8 a = *(const bf16x8*)(sm + (32 * f + l31) * 512 + ((ks * 32 + hi * 16) ^ sw9));
                acc[f] = __builtin_amdgcn_mfma_f32_32x32x16_bf16(a, Bh[ks], acc[f], 0, 0, 0);
            }
#pragma unroll
        for (int f = 0; f < 7; ++f) {
#pragma unroll
            for (int r = 0; r < 16; ++r) acc[f][r] = fmaxf(acc[f][r], 0.f);
            Bh2[2 * f] = packhalf(acc[f], 0);
            if (f < 6) Bh2[2 * f + 1] = packhalf(acc[f], 8);
        }
    }
    __syncthreads();

    // ---- phase C: stage W3' [64][256] and U1h [128][128]
    for (int i = tid; i < 64 * 256; i += 256) {
        int n = i >> 8, k = i & 255;
        float v = (k < 200) ? W3[k * 64 + n] : 0.f;
        *(unsigned short*)(sm + n * 512 + ((k * 2) ^ ((n & 31) << 4))) = f2bf(v);
    }
    for (int i = tid; i < 128 * 128; i += 256) {
        int n = i >> 7, k = i & 127;
        float v = (n < 100 && k < 64) ? U1[(128 + k) * 100 + n] : 0.f;
        *(unsigned short*)(sm + 32768 + n * 256 + ((k * 2) ^ ((n & 15) << 4))) = f2bf(v);
    }
    __syncthreads();

    // ---- layer 3: h3 = relu(h2@W3 + b3) -> B4[4] (K=64)
    bf16x8 B4[4];
    {
        f32x16 acc[2];
#pragma unroll
        for (int f = 0; f < 2; ++f)
#pragma unroll
            for (int r = 0; r < 16; ++r)
                acc[f][r] = ((float*)(sm + EB3))[32 * f + (r & 3) + 8 * (r >> 2) + 4 * hi];
#pragma unroll
        for (int ks = 0; ks < 13; ++ks)
#pragma unroll
            for (int f = 0; f < 2; ++f) {
                bf16x8 a = *(const bf16x8*)(sm + (32 * f + l31) * 512 + ((ks * 32 + hi * 16) ^ sw9));
                acc[f] = __builtin_amdgcn_mfma_f32_32x32x16_bf16(a, Bh2[ks], acc[f], 0, 0, 0);
            }
#pragma unroll
        for (int f = 0; f < 2; ++f) {
#pragma unroll
            for (int r = 0; r < 16; ++r) acc[f][r] = fmaxf(acc[f][r], 0.f);
            B4[2 * f]     = packhalf(acc[f], 0);
            B4[2 * f + 1] = packhalf(acc[f], 8);
        }
    }

    // ---- e = h3 @ U1h + c1 ; e[100] = 1 (carrier)
    {
        f32x16 ae[4];
#pragma unroll
        for (int f = 0; f < 4; ++f)
#pragma unroll
            for (int r = 0; r < 16; ++r)
                ae[f][r] = ((float*)(sm + EC1))[32 * f + (r & 3) + 8 * (r >> 2) + 4 * hi];
#pragma unroll
        for (int ks = 0; ks < 4; ++ks)
#pragma unroll
            for (int f = 0; f < 4; ++f) {
                bf16x8 a = *(const bf16x8*)(sm + 32768 + (32 * f + l31) * 256 + ((ks * 32 + hi * 16) ^ sw8));
                ae[f] = __builtin_amdgcn_mfma_f32_32x32x16_bf16(a, B4[ks], ae[f], 0, 0, 0);
            }
#pragma unroll
        for (int f = 0; f < 4; ++f)
#pragma unroll
            for (int r = 0; r < 16; r += 2) {
                int n = 32 * f + (r & 3) + 8 * (r >> 2) + 4 * hi;
                float v0 = ae[f][r], v1 = ae[f][r + 1];
                if (n == 100) v0 = 1.f;   // bias carrier for the main kernel
                *(unsigned*)(e16 + brow * 128 + n) = pkbf(v0, v1);
            }
    }
}

// ---------------- main fused UMNN kernel (16 waves, barrier-free pipelines) ----
__global__ __launch_bounds__(1024, 2) void umnn_main(
    const float* __restrict__ x,
    const unsigned char* __restrict__ ws, float* __restrict__ out)
{
    extern __shared__ char sm[];
    float* sX = (float*)(sm + OFF_X);   // [8][128]
    float* sG = (float*)(sm + OFF_G);
    float* sE = (float*)(sm + OFF_E);
    float* sP = (float*)(sm + OFF_P);
    const int tid = threadIdx.x;
    const int lane = tid & 63, wid = tid >> 6;
    const int l31 = lane & 31, hi = lane >> 5;
    const int b8 = blockIdx.x * ROWS_PB;   // grid = 256

    // ---- stage weights (swizzled) + per-row vectors
    {
        const uint4* src = (const uint4*)(ws + WM_OFF);   // 6144 x 16B
        for (int ci = tid; ci < 6144; ci += 1024) {
            int m = ci >> 11, wi = ci & 2047, n = wi >> 4, part = wi & 15;
            uint4 v = src[ci];
            *(uint4*)(sm + m * 32768 + n * 256 + ((part * 16) ^ ((n & 15) << 4))) = v;
        }
        const unsigned short* g16 = (const unsigned short*)(ws + G_OFF);
        const unsigned short* e16 = (const unsigned short*)(ws + E_OFF);
        {
            int r = tid >> 7, d = tid & 127;   // 1024 threads = 8*128
            sX[tid] = x[(b8 + r) * 128 + d];
            sG[tid] = bf2f(g16[(b8 + r) * 128 + d]);
            sE[tid] = bf2f(e16[(b8 + r) * 128 + d]);
        }
    }
    __syncthreads();

    const int row = wid >> 1, half = wid & 1;
    const float* gR = sG + row * 128;
    const float* eR = sE + row * 128;
    const float* xR = sX + row * 128;
    const int sw = (l31 & 15) << 4;
    const char* wB2 = sm;
    const char* wB3 = sm + 32768;
    const char* wB4 = sm + 65536;

    float sumF = 0.f;

#pragma unroll 1
    for (int s = 0; s < 5; ++s) {
        const int t = half * 160 + s * 32 + l31;
        const float tt = ((float)t + 0.5f) * (1.f / 300.f);

        // ---- genA: B[ks] = bf16(relu(tt*g + e)), ks 0..6 (k 112..127 zero)
        bf16x8 B[7];
#pragma unroll
        for (int ks = 0; ks < 7; ++ks) {
            const int k0 = ks * 16 + hi * 8;
            f32x4 g0 = *(const f32x4*)(gR + k0);
            f32x4 g1 = *(const f32x4*)(gR + k0 + 4);
            f32x4 e0 = *(const f32x4*)(eR + k0);
            f32x4 e1 = *(const f32x4*)(eR + k0 + 4);
            float a0 = fmaxf(fmaf(tt, g0[0], e0[0]), 0.f);
            float a1 = fmaxf(fmaf(tt, g0[1], e0[1]), 0.f);
            float a2 = fmaxf(fmaf(tt, g0[2], e0[2]), 0.f);
            float a3 = fmaxf(fmaf(tt, g0[3], e0[3]), 0.f);
            float a4 = fmaxf(fmaf(tt, g1[0], e1[0]), 0.f);
            float a5 = fmaxf(fmaf(tt, g1[1], e1[1]), 0.f);
            float a6 = fmaxf(fmaf(tt, g1[2], e1[2]), 0.f);
            float a7 = fmaxf(fmaf(tt, g1[3], e1[3]), 0.f);
            U4B u;
            u.u[0] = pkbf(a0, a1); u.u[1] = pkbf(a2, a3);
            u.u[2] = pkbf(a4, a5); u.u[3] = pkbf(a6, a7);
            B[ks] = u.v;
        }

        // ---- layers 2 and 3: GEMM + relu + in-register repack
#pragma unroll
        for (int L = 0; L < 2; ++L) {
            const char* wb = (L == 0) ? wB2 : wB3;
            f32x16 acc[4];
#pragma unroll
            for (int f = 0; f < 4; ++f) acc[f] = zero16();
#pragma unroll
            for (int ks = 0; ks < 7; ++ks) {
                const int ko = ks * 32 + hi * 16;
#pragma unroll
                for (int f = 0; f < 4; ++f) {
                    bf16x8 a = *(const bf16x8*)(wb + (32 * f + l31) * 256 + (ko ^ sw));
                    acc[f] = __builtin_amdgcn_mfma_f32_32x32x16_bf16(a, B[ks], acc[f], 0, 0, 0);
                }
            }
#pragma unroll
            for (int f = 0; f < 4; ++f) {
#pragma unroll
                for (int r = 0; r < 16; ++r) acc[f][r] = fmaxf(acc[f][r], 0.f);
                B[2 * f] = packhalf(acc[f], 0);
                if (f < 3) B[2 * f + 1] = packhalf(acc[f], 8);
            }
        }

        // ---- layer 4 + fused elu(p)+1 dot x
        float sdot = 0.f;
#pragma unroll
        for (int f = 0; f < 4; ++f) {
            f32x16 acc = zero16();
#pragma unroll
            for (int ks = 0; ks < 7; ++ks) {
                const int ko = ks * 32 + hi * 16;
                bf16x8 a = *(const bf16x8*)(wB4 + (32 * f + l31) * 256 + (ko ^ sw));
                acc = __builtin_amdgcn_mfma_f32_32x32x16_bf16(a, B[ks], acc, 0, 0, 0);
            }
#pragma unroll
            for (int q = 0; q < 4; ++q) {
                const int n0 = f * 32 + q * 8 + hi * 4;
                f32x4 xv = *(const f32x4*)(xR + n0);
#pragma unroll
                for (int i = 0; i < 4; ++i) {
                    float p = acc[q * 4 + i];
                    float fv = (p > 0.f) ? (p + 1.f) : __expf(p);   // elu+1
                    sdot = fmaf(fv, xv[i], sdot);
                }
            }
        }
        if (t < TSTEPS) sumF += sdot;
    }

    // ---- reduce: wave -> row pairs -> sigmoid
#pragma unroll
    for (int off = 32; off >= 1; off >>= 1) sumF += __shfl_xor(sumF, off);
    if (lane == 0) sP[wid] = sumF;
    __syncthreads();
    if (tid < ROWS_PB) {
        float F = (sP[tid * 2] + sP[tid * 2 + 1]) * (1.f / 300.f);
        out[b8 + tid] = 1.f / (1.f + __expf(-F));
    }
}

// ---------------- launch ----------------
extern "C" void kernel_launch(void* const* d_in, const int* in_sizes, int n_in,
                              void* d_out, int out_size, void* d_ws, size_t ws_size,
                              hipStream_t stream)
{
    const float* x  = (const float*)d_in[0];
    const float* W1 = (const float*)d_in[1];
    const float* b1 = (const float*)d_in[2];
    const float* W2 = (const float*)d_in[3];
    const float* b2 = (const float*)d_in[4];
    const float* W3 = (const float*)d_in[5];
    const float* b3 = (const float*)d_in[6];
    const float* U1 = (const float*)d_in[7];
    const float* c1 = (const float*)d_in[8];
    const float* U2 = (const float*)d_in[9];
    const float* c2 = (const float*)d_in[10];
    const float* U3 = (const float*)d_in[11];
    const float* c3 = (const float*)d_in[12];
    const float* U4 = (const float*)d_in[13];
    const float* c4 = (const float*)d_in[14];
    float* out = (float*)d_out;
    unsigned char* ws = (unsigned char*)d_ws;

    prep_kernel<<<24, 256, 0, stream>>>(U2, c2, U3, c3, U4, c4, ws);
    hipFuncSetAttribute((const void*)embed2,
                        hipFuncAttributeMaxDynamicSharedMemorySize, SMEM_E);
    embed2<<<16, 256, SMEM_E, stream>>>(x, W1, b1, W2, b2, W3, b3, U1, c1, ws);
    hipFuncSetAttribute((const void*)umnn_main,
                        hipFuncAttributeMaxDynamicSharedMemorySize, SMEM_M);
    umnn_main<<<BATCH / ROWS_PB, 1024, SMEM_M, stream>>>(x, ws, out);
}

// Round 5
// 168.083 us; speedup vs baseline: 1.4288x; 1.4288x over previous
//
#include <hip/hip_runtime.h>

// ---------------- types / helpers ----------------
typedef __attribute__((ext_vector_type(8))) short bf16x8;   // 8 bf16 = 4 VGPR
typedef __attribute__((ext_vector_type(4))) float f32x4;
typedef __attribute__((ext_vector_type(16))) float f32x16;
typedef int v2i __attribute__((ext_vector_type(2)));

union U4B { unsigned u[4]; bf16x8 v; };

__device__ __forceinline__ unsigned short f2bf(float f) {
    union { float f; unsigned u; } v; v.f = f;
    unsigned r = v.u + 0x7fffu + ((v.u >> 16) & 1u);   // RNE
    return (unsigned short)(r >> 16);
}
__device__ __forceinline__ float bf2f(unsigned short s) {
    union { unsigned u; float f; } v; v.u = ((unsigned)s) << 16; return v.f;
}
__device__ __forceinline__ unsigned pkbf(float a, float b) {
    unsigned r;
    asm("v_cvt_pk_bf16_f32 %0, %1, %2" : "=v"(r) : "v"(a), "v"(b));
    return r;
}
// C-frag half (regs base..base+7) -> B-frag of the next layer (verified r3/r4)
__device__ __forceinline__ bf16x8 packhalf(const f32x16& a, int base) {
    unsigned u  = pkbf(a[base + 0], a[base + 1]);
    unsigned u2 = pkbf(a[base + 2], a[base + 3]);
    unsigned v  = pkbf(a[base + 4], a[base + 5]);
    unsigned v2 = pkbf(a[base + 6], a[base + 7]);
    v2i r1 = __builtin_amdgcn_permlane32_swap(u, v, false, false);
    v2i r2 = __builtin_amdgcn_permlane32_swap(u2, v2, false, false);
    U4B b; b.u[0] = r1.x; b.u[1] = r2.x; b.u[2] = r1.y; b.u[3] = r2.y;
    return b.v;
}
__device__ __forceinline__ f32x16 zero16() {
    f32x16 v;
#pragma unroll
    for (int i = 0; i < 16; ++i) v[i] = 0.f;
    return v;
}

// ---------------- problem constants ----------------
#define BATCH   2048
#define TSTEPS  300
#define ROWS_PB 8            // batch rows per main block (16 waves)
// workspace layout (bytes)
#define WM_OFF   0           // 3 * 128*128 bf16 main weights (bias@k=100, carrier n=100)
#define G_OFF    98304       // 2048*128 bf16
#define E_OFF    622592      // 2048*128 bf16 (ends 1146880)
#define EW1_OFF  1146880     // [224][128] bf16 = 57344
#define EU1X_OFF 1204224     // [128][128] bf16 = 32768
#define EW2_OFF  1236992     // [224][256] bf16 = 114688
#define EW3_OFF  1351680     // [64][256]  bf16 = 32768
#define EU1H_OFF 1384448     // [128][128] bf16 = 32768
#define EB_OFF   1417216     // 640 f32: b1'[224] b2'[224] b3[64] c1'[128]
// main-kernel LDS (bytes)
#define OFF_X   98304        // 8*128 f32
#define OFF_G   102400
#define OFF_E   106496
#define OFF_P   110592       // 16 f32 wave partials
#define SMEM_M  110656
// embed-kernel LDS (bytes): staging 0..114688, biases after (persist all phases)
#define EB1     114688       // 224 f32
#define EB2     115584       // 224 f32
#define EB3     116480       // 64 f32
#define EC1     116736       // 128 f32
#define SMEM_E  117248

// ---------------- prep: ALL weight conversion, source-coalesced ----------------
// Index decomposition is k-major / n-minor so consecutive THREADS read
// consecutive SOURCE addresses (coalesced); the 2B writes scatter (no stall).
__global__ __launch_bounds__(256) void prep_kernel(
    const float* __restrict__ W1, const float* __restrict__ b1,
    const float* __restrict__ W2, const float* __restrict__ b2,
    const float* __restrict__ W3, const float* __restrict__ b3,
    const float* __restrict__ U1, const float* __restrict__ c1,
    const float* __restrict__ U2, const float* __restrict__ c2,
    const float* __restrict__ U3, const float* __restrict__ c3,
    const float* __restrict__ U4, const float* __restrict__ c4,
    unsigned char* __restrict__ ws)
{
    const int NT = 128 * 256;
    const int gid = blockIdx.x * 256 + threadIdx.x;
    unsigned short* w16 = (unsigned short*)ws;

    // main weights W2',W3',W4' [n][k] 128x128 each; bias@k=100, carrier(100,100)=1
    for (int j = gid; j < 3 * 128 * 128; j += NT) {
        int m = j >> 14, r = j & 16383;
        int k = r >> 7, n = r & 127;
        float v = 0.f;
        if (m == 2) {
            if (k < 100)       v = U4[k * 128 + n];
            else if (k == 100) v = c4[n];
        } else {
            const float* U = m ? U3 : U2;
            const float* c = m ? c3 : c2;
            if (k < 100)       { if (n < 100) v = U[k * 100 + n]; }
            else if (k == 100) { if (n < 100) v = c[n]; else if (n == 100) v = 1.f; }
        }
        w16[(WM_OFF >> 1) + m * 16384 + n * 128 + k] = f2bf(v);
    }
    // W1' [224][128]
    for (int j = gid; j < 128 * 224; j += NT) {
        int k = j / 224, n = j % 224;
        float v = (n < 200) ? W1[k * 200 + n] : 0.f;
        w16[(EW1_OFF >> 1) + n * 128 + k] = f2bf(v);
    }
    // U1x [128][128]
    for (int j = gid; j < 128 * 128; j += NT) {
        int k = j >> 7, n = j & 127;
        float v = (n < 100) ? U1[k * 100 + n] : 0.f;
        w16[(EU1X_OFF >> 1) + n * 128 + k] = f2bf(v);
    }
    // U1h [128][128] (k<64 real)
    for (int j = gid; j < 128 * 128; j += NT) {
        int k = j >> 7, n = j & 127;
        float v = (k < 64 && n < 100) ? U1[(128 + k) * 100 + n] : 0.f;
        w16[(EU1H_OFF >> 1) + n * 128 + k] = f2bf(v);
    }
    // W2' [224][256]
    for (int j = gid; j < 256 * 224; j += NT) {
        int k = j / 224, n = j % 224;
        float v = (k < 200 && n < 200) ? W2[k * 200 + n] : 0.f;
        w16[(EW2_OFF >> 1) + n * 256 + k] = f2bf(v);
    }
    // W3' [64][256]
    for (int j = gid; j < 256 * 64; j += NT) {
        int k = j >> 6, n = j & 63;
        float v = (k < 200) ? W3[k * 64 + n] : 0.f;
        w16[(EW3_OFF >> 1) + n * 256 + k] = f2bf(v);
    }
    // biases (f32, padded, in LDS-copy order b1',b2',b3,c1')
    if (gid < 640) {
        int j = gid; float v;
        if (j < 224)      v = (j < 200) ? b1[j] : 0.f;
        else if (j < 448) v = (j - 224 < 200) ? b2[j - 224] : 0.f;
        else if (j < 512) v = b3[j - 448];
        else              v = (j - 512 < 100) ? c1[j - 512] : 0.f;
        ((float*)(ws + EB_OFF))[j] = v;
    }
}

// ---------------- embed: MFMA pipeline, wave = 32 batch rows ----------------
// Staging is now coalesced uint4 copies from prep's bf16 ws images.
__global__ __launch_bounds__(256, 1) void embed2(
    const float* __restrict__ x, unsigned char* __restrict__ ws)
{
    extern __shared__ char sm[];
    const int tid = threadIdx.x;
    const int lane = tid & 63, wid = tid >> 6;
    const int l31 = lane & 31, hi = lane >> 5;
    const int brow = blockIdx.x * 128 + wid * 32 + l31;   // grid = 16
    const int sw8 = (l31 & 15) << 4;    // 256B-row swizzle
    const int sw9 = (l31 & 31) << 4;    // 512B-row swizzle

    // biases -> LDS (region persists across phases)
    for (int i = tid; i < 640; i += 256)
        ((float*)(sm + EB1))[i] = ((const float*)(ws + EB_OFF))[i];

    // ---- phase A: W1' [224][128] + U1x [128][128] (swizzled copy)
    {
        const uint4* s1 = (const uint4*)(ws + EW1_OFF);
        for (int ci = tid; ci < 3584; ci += 256) {
            int n = ci >> 4, part = ci & 15;
            *(uint4*)(sm + n * 256 + ((part * 16) ^ ((n & 15) << 4))) = s1[ci];
        }
        const uint4* s2 = (const uint4*)(ws + EU1X_OFF);
        for (int ci = tid; ci < 2048; ci += 256) {
            int n = ci >> 4, part = ci & 15;
            *(uint4*)(sm + 57344 + n * 256 + ((part * 16) ^ ((n & 15) << 4))) = s2[ci];
        }
    }
    __syncthreads();

    // x B-frags (32 rows per wave)
    bf16x8 Bx[8];
    {
        const float* xr = x + brow * 128;
#pragma unroll
        for (int ks = 0; ks < 8; ++ks) {
            const int k0 = ks * 16 + hi * 8;
            f32x4 a = *(const f32x4*)(xr + k0);
            f32x4 b = *(const f32x4*)(xr + k0 + 4);
            U4B u;
            u.u[0] = pkbf(a[0], a[1]); u.u[1] = pkbf(a[2], a[3]);
            u.u[2] = pkbf(b[0], b[1]); u.u[3] = pkbf(b[2], b[3]);
            Bx[ks] = u.v;
        }
    }

    unsigned short* g16 = (unsigned short*)(ws + G_OFF);
    unsigned short* e16 = (unsigned short*)(ws + E_OFF);

    // ---- g = x @ U1x  (no bias, no relu)
    {
        f32x16 ag[4];
#pragma unroll
        for (int f = 0; f < 4; ++f) ag[f] = zero16();
#pragma unroll
        for (int ks = 0; ks < 8; ++ks)
#pragma unroll
            for (int f = 0; f < 4; ++f) {
                bf16x8 a = *(const bf16x8*)(sm + 57344 + (32 * f + l31) * 256 + ((ks * 32 + hi * 16) ^ sw8));
                ag[f] = __builtin_amdgcn_mfma_f32_32x32x16_bf16(a, Bx[ks], ag[f], 0, 0, 0);
            }
#pragma unroll
        for (int f = 0; f < 4; ++f)
#pragma unroll
            for (int r = 0; r < 16; r += 2) {
                int n = 32 * f + (r & 3) + 8 * (r >> 2) + 4 * hi;
                *(unsigned*)(g16 + brow * 128 + n) = pkbf(ag[f][r], ag[f][r + 1]);
            }
    }

    // ---- layer 1: h1 = relu(x@W1 + b1) -> Bh[13] (K=208)
    bf16x8 Bh[13];
    {
        f32x16 acc[7];
#pragma unroll
        for (int f = 0; f < 7; ++f)
#pragma unroll
            for (int r = 0; r < 16; ++r)
                acc[f][r] = ((float*)(sm + EB1))[32 * f + (r & 3) + 8 * (r >> 2) + 4 * hi];
#pragma unroll
        for (int ks = 0; ks < 8; ++ks)
#pragma unroll
            for (int f = 0; f < 7; ++f) {
                bf16x8 a = *(const bf16x8*)(sm + (32 * f + l31) * 256 + ((ks * 32 + hi * 16) ^ sw8));
                acc[f] = __builtin_amdgcn_mfma_f32_32x32x16_bf16(a, Bx[ks], acc[f], 0, 0, 0);
            }
#pragma unroll
        for (int f = 0; f < 7; ++f) {
#pragma unroll
            for (int r = 0; r < 16; ++r) acc[f][r] = fmaxf(acc[f][r], 0.f);
            Bh[2 * f] = packhalf(acc[f], 0);
            if (f < 6) Bh[2 * f + 1] = packhalf(acc[f], 8);
        }
    }
    __syncthreads();

    // ---- phase B: W2' [224][256]
    {
        const uint4* s3 = (const uint4*)(ws + EW2_OFF);
        for (int ci = tid; ci < 7168; ci += 256) {
            int n = ci >> 5, part = ci & 31;
            *(uint4*)(sm + n * 512 + ((part * 16) ^ ((n & 31) << 4))) = s3[ci];
        }
    }
    __syncthreads();

    // ---- layer 2: h2 = relu(h1@W2 + b2) -> Bh2[13]
    bf16x8 Bh2[13];
    {
        f32x16 acc[7];
#pragma unroll
        for (int f = 0; f < 7; ++f)
#pragma unroll
            for (int r = 0; r < 16; ++r)
                acc[f][r] = ((float*)(sm + EB2))[32 * f + (r & 3) + 8 * (r >> 2) + 4 * hi];
#pragma unroll
        for (int ks = 0; ks < 13; ++ks)
#pragma unroll
            for (int f = 0; f < 7; ++f) {
                bf16x8 a = *(const bf16x8*)(sm + (32 * f + l31) * 512 + ((ks * 32 + hi * 16) ^ sw9));
                acc[f] = __builtin_amdgcn_mfma_f32_32x32x16_bf16(a, Bh[ks], acc[f], 0, 0, 0);
            }
#pragma unroll
        for (int f = 0; f < 7; ++f) {
#pragma unroll
            for (int r = 0; r < 16; ++r) acc[f][r] = fmaxf(acc[f][r], 0.f);
            Bh2[2 * f] = packhalf(acc[f], 0);
            if (f < 6) Bh2[2 * f + 1] = packhalf(acc[f], 8);
        }
    }
    __syncthreads();

    // ---- phase C: W3' [64][256] + U1h [128][128]
    {
        const uint4* s4 = (const uint4*)(ws + EW3_OFF);
        for (int ci = tid; ci < 2048; ci += 256) {
            int n = ci >> 5, part = ci & 31;
            *(uint4*)(sm + n * 512 + ((part * 16) ^ ((n & 31) << 4))) = s4[ci];
        }
        const uint4* s5 = (const uint4*)(ws + EU1H_OFF);
        for (int ci = tid; ci < 2048; ci += 256) {
            int n = ci >> 4, part = ci & 15;
            *(uint4*)(sm + 32768 + n * 256 + ((part * 16) ^ ((n & 15) << 4))) = s5[ci];
        }
    }
    __syncthreads();

    // ---- layer 3: h3 = relu(h2@W3 + b3) -> B4[4] (K=64)
    bf16x8 B4[4];
    {
        f32x16 acc[2];
#pragma unroll
        for (int f = 0; f < 2; ++f)
#pragma unroll
            for (int r = 0; r < 16; ++r)
                acc[f][r] = ((float*)(sm + EB3))[32 * f + (r & 3) + 8 * (r >> 2) + 4 * hi];
#pragma unroll
        for (int ks = 0; ks < 13; ++ks)
#pragma unroll
            for (int f = 0; f < 2; ++f) {
                bf16x8 a = *(const bf16x8*)(sm + (32 * f + l31) * 512 + ((ks * 32 + hi * 16) ^ sw9));
                acc[f] = __builtin_amdgcn_mfma_f32_32x32x16_bf16(a, Bh2[ks], acc[f], 0, 0, 0);
            }
#pragma unroll
        for (int f = 0; f < 2; ++f) {
#pragma unroll
            for (int r = 0; r < 16; ++r) acc[f][r] = fmaxf(acc[f][r], 0.f);
            B4[2 * f]     = packhalf(acc[f], 0);
            B4[2 * f + 1] = packhalf(acc[f], 8);
        }
    }

    // ---- e = h3 @ U1h + c1 ; e[100] = 1 (carrier)
    {
        f32x16 ae[4];
#pragma unroll
        for (int f = 0; f < 4; ++f)
#pragma unroll
            for (int r = 0; r < 16; ++r)
                ae[f][r] = ((float*)(sm + EC1))[32 * f + (r & 3) + 8 * (r >> 2) + 4 * hi];
#pragma unroll
        for (int ks = 0; ks < 4; ++ks)
#pragma unroll
            for (int f = 0; f < 4; ++f) {
                bf16x8 a = *(const bf16x8*)(sm + 32768 + (32 * f + l31) * 256 + ((ks * 32 + hi * 16) ^ sw8));
                ae[f] = __builtin_amdgcn_mfma_f32_32x32x16_bf16(a, B4[ks], ae[f], 0, 0, 0);
            }
#pragma unroll
        for (int f = 0; f < 4; ++f)
#pragma unroll
            for (int r = 0; r < 16; r += 2) {
                int n = 32 * f + (r & 3) + 8 * (r >> 2) + 4 * hi;
                float v0 = ae[f][r], v1 = ae[f][r + 1];
                if (n == 100) v0 = 1.f;   // bias carrier for the main kernel
                *(unsigned*)(e16 + brow * 128 + n) = pkbf(v0, v1);
            }
    }
}

// ---------------- main fused UMNN kernel (16 waves, barrier-free pipelines) ----
// __launch_bounds__(1024, 1): one 16-wave block/CU -> VGPR cap 128 (body needs
// ~88-110). (1024,2) was interpreted as 2 blocks/CU -> 64-VGPR cap -> spills
// (r4: WRITE_SIZE 2 MB, MfmaUtil 4%). Do not raise the second arg.
__global__ __launch_bounds__(1024, 1) void umnn_main(
    const float* __restrict__ x,
    const unsigned char* __restrict__ ws, float* __restrict__ out)
{
    extern __shared__ char sm[];
    float* sX = (float*)(sm + OFF_X);   // [8][128]
    float* sG = (float*)(sm + OFF_G);
    float* sE = (float*)(sm + OFF_E);
    float* sP = (float*)(sm + OFF_P);
    const int tid = threadIdx.x;
    const int lane = tid & 63, wid = tid >> 6;
    const int l31 = lane & 31, hi = lane >> 5;
    const int b8 = blockIdx.x * ROWS_PB;   // grid = 256

    // ---- stage weights (swizzled) + per-row vectors
    {
        const uint4* src = (const uint4*)(ws + WM_OFF);   // 6144 x 16B
        for (int ci = tid; ci < 6144; ci += 1024) {
            int m = ci >> 11, wi = ci & 2047, n = wi >> 4, part = wi & 15;
            uint4 v = src[ci];
            *(uint4*)(sm + m * 32768 + n * 256 + ((part * 16) ^ ((n & 15) << 4))) = v;
        }
        const unsigned short* g16 = (const unsigned short*)(ws + G_OFF);
        const unsigned short* e16 = (const unsigned short*)(ws + E_OFF);
        {
            int r = tid >> 7, d = tid & 127;   // 1024 threads = 8*128
            sX[tid] = x[(b8 + r) * 128 + d];
            sG[tid] = bf2f(g16[(b8 + r) * 128 + d]);
            sE[tid] = bf2f(e16[(b8 + r) * 128 + d]);
        }
    }
    __syncthreads();

    const int row = wid >> 1, half = wid & 1;
    const float* gR = sG + row * 128;
    const float* eR = sE + row * 128;
    const float* xR = sX + row * 128;
    const int sw = (l31 & 15) << 4;
    const char* wB2 = sm;
    const char* wB3 = sm + 32768;
    const char* wB4 = sm + 65536;

    float sumF = 0.f;

#pragma unroll 1
    for (int s = 0; s < 5; ++s) {
        const int t = half * 160 + s * 32 + l31;
        const float tt = ((float)t + 0.5f) * (1.f / 300.f);

        // ---- genA: B[ks] = bf16(relu(tt*g + e)), ks 0..6 (k 112..127 zero)
        bf16x8 B[7];
#pragma unroll
        for (int ks = 0; ks < 7; ++ks) {
            const int k0 = ks * 16 + hi * 8;
            f32x4 g0 = *(const f32x4*)(gR + k0);
            f32x4 g1 = *(const f32x4*)(gR + k0 + 4);
            f32x4 e0 = *(const f32x4*)(eR + k0);
            f32x4 e1 = *(const f32x4*)(eR + k0 + 4);
            float a0 = fmaxf(fmaf(tt, g0[0], e0[0]), 0.f);
            float a1 = fmaxf(fmaf(tt, g0[1], e0[1]), 0.f);
            float a2 = fmaxf(fmaf(tt, g0[2], e0[2]), 0.f);
            float a3 = fmaxf(fmaf(tt, g0[3], e0[3]), 0.f);
            float a4 = fmaxf(fmaf(tt, g1[0], e1[0]), 0.f);
            float a5 = fmaxf(fmaf(tt, g1[1], e1[1]), 0.f);
            float a6 = fmaxf(fmaf(tt, g1[2], e1[2]), 0.f);
            float a7 = fmaxf(fmaf(tt, g1[3], e1[3]), 0.f);
            U4B u;
            u.u[0] = pkbf(a0, a1); u.u[1] = pkbf(a2, a3);
            u.u[2] = pkbf(a4, a5); u.u[3] = pkbf(a6, a7);
            B[ks] = u.v;
        }

        // ---- layers 2 and 3: GEMM + relu + in-register repack
#pragma unroll
        for (int L = 0; L < 2; ++L) {
            const char* wb = (L == 0) ? wB2 : wB3;
            f32x16 acc[4];
#pragma unroll
            for (int f = 0; f < 4; ++f) acc[f] = zero16();
#pragma unroll
            for (int ks = 0; ks < 7; ++ks) {
                const int ko = ks * 32 + hi * 16;
#pragma unroll
                for (int f = 0; f < 4; ++f) {
                    bf16x8 a = *(const bf16x8*)(wb + (32 * f + l31) * 256 + (ko ^ sw));
                    acc[f] = __builtin_amdgcn_mfma_f32_32x32x16_bf16(a, B[ks], acc[f], 0, 0, 0);
                }
            }
#pragma unroll
            for (int f = 0; f < 4; ++f) {
#pragma unroll
                for (int r = 0; r < 16; ++r) acc[f][r] = fmaxf(acc[f][r], 0.f);
                B[2 * f] = packhalf(acc[f], 0);
                if (f < 3) B[2 * f + 1] = packhalf(acc[f], 8);
            }
        }

        // ---- layer 4 + fused elu(p)+1 dot x
        float sdot = 0.f;
#pragma unroll
        for (int f = 0; f < 4; ++f) {
            f32x16 acc = zero16();
#pragma unroll
            for (int ks = 0; ks < 7; ++ks) {
                const int ko = ks * 32 + hi * 16;
                bf16x8 a = *(const bf16x8*)(wB4 + (32 * f + l31) * 256 + (ko ^ sw));
                acc = __builtin_amdgcn_mfma_f32_32x32x16_bf16(a, B[ks], acc, 0, 0, 0);
            }
#pragma unroll
            for (int q = 0; q < 4; ++q) {
                const int n0 = f * 32 + q * 8 + hi * 4;
                f32x4 xv = *(const f32x4*)(xR + n0);
#pragma unroll
                for (int i = 0; i < 4; ++i) {
                    float p = acc[q * 4 + i];
                    float fv = (p > 0.f) ? (p + 1.f) : __expf(p);   // elu+1
                    sdot = fmaf(fv, xv[i], sdot);
                }
            }
        }
        if (t < TSTEPS) sumF += sdot;
    }

    // ---- reduce: wave -> row pairs -> sigmoid
#pragma unroll
    for (int off = 32; off >= 1; off >>= 1) sumF += __shfl_xor(sumF, off);
    if (lane == 0) sP[wid] = sumF;
    __syncthreads();
    if (tid < ROWS_PB) {
        float F = (sP[tid * 2] + sP[tid * 2 + 1]) * (1.f / 300.f);
        out[b8 + tid] = 1.f / (1.f + __expf(-F));
    }
}

// ---------------- launch ----------------
extern "C" void kernel_launch(void* const* d_in, const int* in_sizes, int n_in,
                              void* d_out, int out_size, void* d_ws, size_t ws_size,
                              hipStream_t stream)
{
    const float* x  = (const float*)d_in[0];
    const float* W1 = (const float*)d_in[1];
    const float* b1 = (const float*)d_in[2];
    const float* W2 = (const float*)d_in[3];
    const float* b2 = (const float*)d_in[4];
    const float* W3 = (const float*)d_in[5];
    const float* b3 = (const float*)d_in[6];
    const float* U1 = (const float*)d_in[7];
    const float* c1 = (const float*)d_in[8];
    const float* U2 = (const float*)d_in[9];
    const float* c2 = (const float*)d_in[10];
    const float* U3 = (const float*)d_in[11];
    const float* c3 = (const float*)d_in[12];
    const float* U4 = (const float*)d_in[13];
    const float* c4 = (const float*)d_in[14];
    float* out = (float*)d_out;
    unsigned char* ws = (unsigned char*)d_ws;

    prep_kernel<<<128, 256, 0, stream>>>(W1, b1, W2, b2, W3, b3, U1, c1,
                                         U2, c2, U3, c3, U4, c4, ws);
    hipFuncSetAttribute((const void*)embed2,
                        hipFuncAttributeMaxDynamicSharedMemorySize, SMEM_E);
    embed2<<<16, 256, SMEM_E, stream>>>(x, ws);
    hipFuncSetAttribute((const void*)umnn_main,
                        hipFuncAttributeMaxDynamicSharedMemorySize, SMEM_M);
    umnn_main<<<BATCH / ROWS_PB, 1024, SMEM_M, stream>>>(x, ws, out);
}

// Round 6
// 161.262 us; speedup vs baseline: 1.4893x; 1.0423x over previous
//
#include <hip/hip_runtime.h>

// ---------------- types / helpers ----------------
typedef __attribute__((ext_vector_type(8))) short bf16x8;   // 8 bf16 = 4 VGPR
typedef __attribute__((ext_vector_type(4))) float f32x4;
typedef __attribute__((ext_vector_type(16))) float f32x16;
typedef int v2i __attribute__((ext_vector_type(2)));

union U4B { unsigned u[4]; bf16x8 v; };

__device__ __forceinline__ unsigned short f2bf(float f) {
    union { float f; unsigned u; } v; v.f = f;
    unsigned r = v.u + 0x7fffu + ((v.u >> 16) & 1u);   // RNE
    return (unsigned short)(r >> 16);
}
__device__ __forceinline__ float bf2f(unsigned short s) {
    union { unsigned u; float f; } v; v.u = ((unsigned)s) << 16; return v.f;
}
__device__ __forceinline__ unsigned pkbf(float a, float b) {
    unsigned r;
    asm("v_cvt_pk_bf16_f32 %0, %1, %2" : "=v"(r) : "v"(a), "v"(b));
    return r;
}
// C-frag half (regs base..base+7) -> B-frag of the next layer (verified r3/r4/r5)
__device__ __forceinline__ bf16x8 packhalf(const f32x16& a, int base) {
    unsigned u  = pkbf(a[base + 0], a[base + 1]);
    unsigned u2 = pkbf(a[base + 2], a[base + 3]);
    unsigned v  = pkbf(a[base + 4], a[base + 5]);
    unsigned v2 = pkbf(a[base + 6], a[base + 7]);
    v2i r1 = __builtin_amdgcn_permlane32_swap(u, v, false, false);
    v2i r2 = __builtin_amdgcn_permlane32_swap(u2, v2, false, false);
    U4B b; b.u[0] = r1.x; b.u[1] = r2.x; b.u[2] = r1.y; b.u[3] = r2.y;
    return b.v;
}
__device__ __forceinline__ f32x16 zero16() {
    f32x16 v;
#pragma unroll
    for (int i = 0; i < 16; ++i) v[i] = 0.f;
    return v;
}

// ---------------- problem constants ----------------
#define BATCH   2048
#define TSTEPS  300
#define ROWS_PB 8            // batch rows per main block (16 waves)
// workspace layout (bytes)
#define WM_OFF   0           // 3 * 128*128 bf16 main weights (bias@k=100, carrier n=100)
#define G_OFF    98304       // 2048*128 bf16
#define E_OFF    622592      // 2048*128 bf16 (ends 1146880)
#define EW1_OFF  1146880     // [224][128] bf16 = 57344
#define EU1X_OFF 1204224     // [128][128] bf16 = 32768
#define EW2_OFF  1236992     // [224][256] bf16 = 114688
#define EW3_OFF  1351680     // [64][256]  bf16 = 32768
#define EU1H_OFF 1384448     // [128][128] bf16 = 32768
#define EB_OFF   1417216     // 640 f32: b1'[224] b2'[224] b3[64] c1'[128]
// main-kernel LDS (bytes)
#define OFF_X   98304        // 8*128 f32
#define OFF_G   102400
#define OFF_E   106496
#define OFF_P   110592       // 16 f32 wave partials
#define SMEM_M  110656
// embed-kernel LDS (bytes): weight staging 0..114688, then act + biases
#define EACT    114688       // [32][256] bf16 = 16384 (XOR-swizzled act handoff)
#define EB1     131072       // 224 f32
#define EB2     131968       // 224 f32
#define EB3     132864       // 64 f32
#define EC1     133120       // 128 f32
#define SMEM_E  133632

// ---------------- prep: ALL weight conversion, source-coalesced ----------------
__global__ __launch_bounds__(256) void prep_kernel(
    const float* __restrict__ W1, const float* __restrict__ b1,
    const float* __restrict__ W2, const float* __restrict__ b2,
    const float* __restrict__ W3, const float* __restrict__ b3,
    const float* __restrict__ U1, const float* __restrict__ c1,
    const float* __restrict__ U2, const float* __restrict__ c2,
    const float* __restrict__ U3, const float* __restrict__ c3,
    const float* __restrict__ U4, const float* __restrict__ c4,
    unsigned char* __restrict__ ws)
{
    const int NT = 128 * 256;
    const int gid = blockIdx.x * 256 + threadIdx.x;
    unsigned short* w16 = (unsigned short*)ws;

    // main weights W2',W3',W4' [n][k] 128x128 each; bias@k=100, carrier(100,100)=1
    for (int j = gid; j < 3 * 128 * 128; j += NT) {
        int m = j >> 14, r = j & 16383;
        int k = r >> 7, n = r & 127;
        float v = 0.f;
        if (m == 2) {
            if (k < 100)       v = U4[k * 128 + n];
            else if (k == 100) v = c4[n];
        } else {
            const float* U = m ? U3 : U2;
            const float* c = m ? c3 : c2;
            if (k < 100)       { if (n < 100) v = U[k * 100 + n]; }
            else if (k == 100) { if (n < 100) v = c[n]; else if (n == 100) v = 1.f; }
        }
        w16[(WM_OFF >> 1) + m * 16384 + n * 128 + k] = f2bf(v);
    }
    // W1' [224][128]
    for (int j = gid; j < 128 * 224; j += NT) {
        int k = j / 224, n = j % 224;
        float v = (n < 200) ? W1[k * 200 + n] : 0.f;
        w16[(EW1_OFF >> 1) + n * 128 + k] = f2bf(v);
    }
    // U1x [128][128]
    for (int j = gid; j < 128 * 128; j += NT) {
        int k = j >> 7, n = j & 127;
        float v = (n < 100) ? U1[k * 100 + n] : 0.f;
        w16[(EU1X_OFF >> 1) + n * 128 + k] = f2bf(v);
    }
    // U1h [128][128] (k<64 real)
    for (int j = gid; j < 128 * 128; j += NT) {
        int k = j >> 7, n = j & 127;
        float v = (k < 64 && n < 100) ? U1[(128 + k) * 100 + n] : 0.f;
        w16[(EU1H_OFF >> 1) + n * 128 + k] = f2bf(v);
    }
    // W2' [224][256]
    for (int j = gid; j < 256 * 224; j += NT) {
        int k = j / 224, n = j % 224;
        float v = (k < 200 && n < 200) ? W2[k * 200 + n] : 0.f;
        w16[(EW2_OFF >> 1) + n * 256 + k] = f2bf(v);
    }
    // W3' [64][256]
    for (int j = gid; j < 256 * 64; j += NT) {
        int k = j >> 6, n = j & 63;
        float v = (k < 200) ? W3[k * 64 + n] : 0.f;
        w16[(EW3_OFF >> 1) + n * 256 + k] = f2bf(v);
    }
    // biases (f32, padded, contiguous: b1'[224] b2'[224] b3[64] c1'[128])
    if (gid < 640) {
        int j = gid; float v;
        if (j < 224)      v = (j < 200) ? b1[j] : 0.f;
        else if (j < 448) v = (j - 224 < 200) ? b2[j - 224] : 0.f;
        else if (j < 512) v = b3[j - 448];
        else              v = (j - 512 < 100) ? c1[j - 512] : 0.f;
        ((float*)(ws + EB_OFF))[j] = v;
    }
}

// ---------------- embed: f-split MFMA pipeline, 64 blocks x 32 rows ----------
// Block = 32 batch rows (col = l31), 4 waves split the output-frag dim each
// layer; activations hand off through a swizzled LDS act buffer [32][256]bf16.
__device__ __forceinline__ void act_store(char* act, int l31, int f, int hi,
                                          const f32x16& a) {
#pragma unroll
    for (int r = 0; r < 16; r += 2) {
        int n = 32 * f + (r & 3) + 8 * (r >> 2) + 4 * hi;
        unsigned u = pkbf(fmaxf(a[r], 0.f), fmaxf(a[r + 1], 0.f));   // relu fused
        *(unsigned*)(act + l31 * 512 + ((n * 2) ^ ((l31 & 7) << 4))) = u;
    }
}
__device__ __forceinline__ bf16x8 act_read(const char* act, int l31, int ks, int hi) {
    return *(const bf16x8*)(act + l31 * 512 + ((ks * 32 + hi * 16) ^ ((l31 & 7) << 4)));
}

__global__ __launch_bounds__(256) void embed2(
    const float* __restrict__ x, unsigned char* __restrict__ ws)
{
    extern __shared__ char sm[];
    char* act = sm + EACT;
    const int tid = threadIdx.x;
    const int lane = tid & 63, wid = tid >> 6;
    const int l31 = lane & 31, hi = lane >> 5;
    const int brow = blockIdx.x * 32 + l31;   // grid = 64
    const int sw8 = (l31 & 15) << 4;    // 256B-row weight swizzle
    const int sw9 = (l31 & 31) << 4;    // 512B-row weight swizzle

    // biases -> LDS (contiguous 640 f32; region persists)
    for (int i = tid; i < 640; i += 256)
        ((float*)(sm + EB1))[i] = ((const float*)(ws + EB_OFF))[i];

    // ---- stage A: W1' [224][128] + U1x [128][128]
    {
        const uint4* s1 = (const uint4*)(ws + EW1_OFF);
        for (int ci = tid; ci < 3584; ci += 256) {
            int n = ci >> 4, part = ci & 15;
            *(uint4*)(sm + n * 256 + ((part * 16) ^ ((n & 15) << 4))) = s1[ci];
        }
        const uint4* s2 = (const uint4*)(ws + EU1X_OFF);
        for (int ci = tid; ci < 2048; ci += 256) {
            int n = ci >> 4, part = ci & 15;
            *(uint4*)(sm + 57344 + n * 256 + ((part * 16) ^ ((n & 15) << 4))) = s2[ci];
        }
    }

    // x B-frags (all waves: same 32 rows)
    bf16x8 Bx[8];
    {
        const float* xr = x + brow * 128;
#pragma unroll
        for (int ks = 0; ks < 8; ++ks) {
            const int k0 = ks * 16 + hi * 8;
            f32x4 a = *(const f32x4*)(xr + k0);
            f32x4 b = *(const f32x4*)(xr + k0 + 4);
            U4B u;
            u.u[0] = pkbf(a[0], a[1]); u.u[1] = pkbf(a[2], a[3]);
            u.u[2] = pkbf(b[0], b[1]); u.u[3] = pkbf(b[2], b[3]);
            Bx[ks] = u.v;
        }
    }
    __syncthreads();

    unsigned short* g16 = (unsigned short*)(ws + G_OFF);
    unsigned short* e16 = (unsigned short*)(ws + E_OFF);

    // ---- g = x @ U1x (frag = wid) -> global, no bias/relu
    {
        f32x16 ag = zero16();
#pragma unroll
        for (int ks = 0; ks < 8; ++ks) {
            bf16x8 a = *(const bf16x8*)(sm + 57344 + (32 * wid + l31) * 256 + ((ks * 32 + hi * 16) ^ sw8));
            ag = __builtin_amdgcn_mfma_f32_32x32x16_bf16(a, Bx[ks], ag, 0, 0, 0);
        }
#pragma unroll
        for (int r = 0; r < 16; r += 2) {
            int n = 32 * wid + (r & 3) + 8 * (r >> 2) + 4 * hi;
            *(unsigned*)(g16 + brow * 128 + n) = pkbf(ag[r], ag[r + 1]);
        }
    }

    // ---- layer 1: frags {wid, wid+4} of relu(x@W1'+b1) -> act
    for (int f = wid; f < 7; f += 4) {
        f32x16 acc;
#pragma unroll
        for (int r = 0; r < 16; ++r)
            acc[r] = ((float*)(sm + EB1))[32 * f + (r & 3) + 8 * (r >> 2) + 4 * hi];
#pragma unroll
        for (int ks = 0; ks < 8; ++ks) {
            bf16x8 a = *(const bf16x8*)(sm + (32 * f + l31) * 256 + ((ks * 32 + hi * 16) ^ sw8));
            acc = __builtin_amdgcn_mfma_f32_32x32x16_bf16(a, Bx[ks], acc, 0, 0, 0);
        }
        act_store(act, l31, f, hi, acc);
    }
    __syncthreads();

    // ---- read Bh (13 frags) ; stage B: W2' [224][256] (disjoint LDS regions)
    bf16x8 Bh[13];
#pragma unroll
    for (int ks = 0; ks < 13; ++ks) Bh[ks] = act_read(act, l31, ks, hi);
    {
        const uint4* s3 = (const uint4*)(ws + EW2_OFF);
        for (int ci = tid; ci < 7168; ci += 256) {
            int n = ci >> 5, part = ci & 31;
            *(uint4*)(sm + n * 512 + ((part * 16) ^ ((n & 31) << 4))) = s3[ci];
        }
    }
    __syncthreads();

    // ---- layer 2: frags {wid, wid+4} of relu(h1@W2'+b2) -> act
    for (int f = wid; f < 7; f += 4) {
        f32x16 acc;
#pragma unroll
        for (int r = 0; r < 16; ++r)
            acc[r] = ((float*)(sm + EB2))[32 * f + (r & 3) + 8 * (r >> 2) + 4 * hi];
#pragma unroll
        for (int ks = 0; ks < 13; ++ks) {
            bf16x8 a = *(const bf16x8*)(sm + (32 * f + l31) * 512 + ((ks * 32 + hi * 16) ^ sw9));
            acc = __builtin_amdgcn_mfma_f32_32x32x16_bf16(a, Bh[ks], acc, 0, 0, 0);
        }
        act_store(act, l31, f, hi, acc);
    }
    __syncthreads();

    // ---- read Bh2 (13 frags) ; stage C: W3' [64][256] + U1h [128][128]
    bf16x8 Bh2[13];
#pragma unroll
    for (int ks = 0; ks < 13; ++ks) Bh2[ks] = act_read(act, l31, ks, hi);
    {
        const uint4* s4 = (const uint4*)(ws + EW3_OFF);
        for (int ci = tid; ci < 2048; ci += 256) {
            int n = ci >> 5, part = ci & 31;
            *(uint4*)(sm + n * 512 + ((part * 16) ^ ((n & 31) << 4))) = s4[ci];
        }
        const uint4* s5 = (const uint4*)(ws + EU1H_OFF);
        for (int ci = tid; ci < 2048; ci += 256) {
            int n = ci >> 4, part = ci & 15;
            *(uint4*)(sm + 32768 + n * 256 + ((part * 16) ^ ((n & 15) << 4))) = s5[ci];
        }
    }
    __syncthreads();

    // ---- layer 3: frags {wid} < 2 of relu(h2@W3'+b3) -> act (n<64)
    for (int f = wid; f < 2; f += 4) {
        f32x16 acc;
#pragma unroll
        for (int r = 0; r < 16; ++r)
            acc[r] = ((float*)(sm + EB3))[32 * f + (r & 3) + 8 * (r >> 2) + 4 * hi];
#pragma unroll
        for (int ks = 0; ks < 13; ++ks) {
            bf16x8 a = *(const bf16x8*)(sm + (32 * f + l31) * 512 + ((ks * 32 + hi * 16) ^ sw9));
            acc = __builtin_amdgcn_mfma_f32_32x32x16_bf16(a, Bh2[ks], acc, 0, 0, 0);
        }
        act_store(act, l31, f, hi, acc);
    }
    __syncthreads();

    // ---- e = h3 @ U1h + c1 (frag = wid) -> global ; e[100]=1 carrier
    {
        f32x16 ae;
#pragma unroll
        for (int r = 0; r < 16; ++r)
            ae[r] = ((float*)(sm + EC1))[32 * wid + (r & 3) + 8 * (r >> 2) + 4 * hi];
        bf16x8 B4[4];
#pragma unroll
        for (int ks = 0; ks < 4; ++ks) B4[ks] = act_read(act, l31, ks, hi);
#pragma unroll
        for (int ks = 0; ks < 4; ++ks) {
            bf16x8 a = *(const bf16x8*)(sm + 32768 + (32 * wid + l31) * 256 + ((ks * 32 + hi * 16) ^ sw8));
            ae = __builtin_amdgcn_mfma_f32_32x32x16_bf16(a, B4[ks], ae, 0, 0, 0);
        }
#pragma unroll
        for (int r = 0; r < 16; r += 2) {
            int n = 32 * wid + (r & 3) + 8 * (r >> 2) + 4 * hi;
            float v0 = ae[r], v1 = ae[r + 1];
            if (wid == 3 && hi == 1 && r == 0) v0 = 1.f;   // n==100 carrier
            *(unsigned*)(e16 + brow * 128 + n) = pkbf(v0, v1);
        }
    }
}

// ---------------- main fused UMNN kernel (16 waves, barrier-free pipelines) ----
// amdgpu_waves_per_eu(4,4): min=4 caps VGPR at 128 (body needs ~110) and stops
// the backend's 8-wave/EU heuristic that forced 64 VGPR + 2MB spills (r4/r5).
__global__ __launch_bounds__(1024)
__attribute__((amdgpu_waves_per_eu(4, 4))) void umnn_main(
    const float* __restrict__ x,
    const unsigned char* __restrict__ ws, float* __restrict__ out)
{
    extern __shared__ char sm[];
    float* sX = (float*)(sm + OFF_X);   // [8][128]
    float* sG = (float*)(sm + OFF_G);
    float* sE = (float*)(sm + OFF_E);
    float* sP = (float*)(sm + OFF_P);
    const int tid = threadIdx.x;
    const int lane = tid & 63, wid = tid >> 6;
    const int l31 = lane & 31, hi = lane >> 5;
    const int b8 = blockIdx.x * ROWS_PB;   // grid = 256

    // ---- stage weights (swizzled) + per-row vectors
    {
        const uint4* src = (const uint4*)(ws + WM_OFF);   // 6144 x 16B
        for (int ci = tid; ci < 6144; ci += 1024) {
            int m = ci >> 11, wi = ci & 2047, n = wi >> 4, part = wi & 15;
            uint4 v = src[ci];
            *(uint4*)(sm + m * 32768 + n * 256 + ((part * 16) ^ ((n & 15) << 4))) = v;
        }
        const unsigned short* g16 = (const unsigned short*)(ws + G_OFF);
        const unsigned short* e16 = (const unsigned short*)(ws + E_OFF);
        {
            int r = tid >> 7, d = tid & 127;   // 1024 threads = 8*128
            sX[tid] = x[(b8 + r) * 128 + d];
            sG[tid] = bf2f(g16[(b8 + r) * 128 + d]);
            sE[tid] = bf2f(e16[(b8 + r) * 128 + d]);
        }
    }
    __syncthreads();

    const int row = wid >> 1, half = wid & 1;
    const float* gR = sG + row * 128;
    const float* eR = sE + row * 128;
    const float* xR = sX + row * 128;
    const int sw = (l31 & 15) << 4;
    const char* wB2 = sm;
    const char* wB3 = sm + 32768;
    const char* wB4 = sm + 65536;

    float sumF = 0.f;

#pragma unroll 1
    for (int s = 0; s < 5; ++s) {
        const int t = half * 160 + s * 32 + l31;
        const float tt = ((float)t + 0.5f) * (1.f / 300.f);

        // ---- genA: B[ks] = bf16(relu(tt*g + e)), ks 0..6 (k 112..127 zero)
        bf16x8 B[7];
#pragma unroll
        for (int ks = 0; ks < 7; ++ks) {
            const int k0 = ks * 16 + hi * 8;
            f32x4 g0 = *(const f32x4*)(gR + k0);
            f32x4 g1 = *(const f32x4*)(gR + k0 + 4);
            f32x4 e0 = *(const f32x4*)(eR + k0);
            f32x4 e1 = *(const f32x4*)(eR + k0 + 4);
            float a0 = fmaxf(fmaf(tt, g0[0], e0[0]), 0.f);
            float a1 = fmaxf(fmaf(tt, g0[1], e0[1]), 0.f);
            float a2 = fmaxf(fmaf(tt, g0[2], e0[2]), 0.f);
            float a3 = fmaxf(fmaf(tt, g0[3], e0[3]), 0.f);
            float a4 = fmaxf(fmaf(tt, g1[0], e1[0]), 0.f);
            float a5 = fmaxf(fmaf(tt, g1[1], e1[1]), 0.f);
            float a6 = fmaxf(fmaf(tt, g1[2], e1[2]), 0.f);
            float a7 = fmaxf(fmaf(tt, g1[3], e1[3]), 0.f);
            U4B u;
            u.u[0] = pkbf(a0, a1); u.u[1] = pkbf(a2, a3);
            u.u[2] = pkbf(a4, a5); u.u[3] = pkbf(a6, a7);
            B[ks] = u.v;
        }

        // ---- layers 2 and 3: GEMM + relu + in-register repack
#pragma unroll
        for (int L = 0; L < 2; ++L) {
            const char* wb = (L == 0) ? wB2 : wB3;
            f32x16 acc[4];
#pragma unroll
            for (int f = 0; f < 4; ++f) acc[f] = zero16();
#pragma unroll
            for (int ks = 0; ks < 7; ++ks) {
                const int ko = ks * 32 + hi * 16;
#pragma unroll
                for (int f = 0; f < 4; ++f) {
                    bf16x8 a = *(const bf16x8*)(wb + (32 * f + l31) * 256 + (ko ^ sw));
                    acc[f] = __builtin_amdgcn_mfma_f32_32x32x16_bf16(a, B[ks], acc[f], 0, 0, 0);
                }
            }
#pragma unroll
            for (int f = 0; f < 4; ++f) {
#pragma unroll
                for (int r = 0; r < 16; ++r) acc[f][r] = fmaxf(acc[f][r], 0.f);
                B[2 * f] = packhalf(acc[f], 0);
                if (f < 3) B[2 * f + 1] = packhalf(acc[f], 8);
            }
        }

        // ---- layer 4 + fused elu(p)+1 dot x
        float sdot = 0.f;
#pragma unroll
        for (int f = 0; f < 4; ++f) {
            f32x16 acc = zero16();
#pragma unroll
            for (int ks = 0; ks < 7; ++ks) {
                const int ko = ks * 32 + hi * 16;
                bf16x8 a = *(const bf16x8*)(wB4 + (32 * f + l31) * 256 + (ko ^ sw));
                acc = __builtin_amdgcn_mfma_f32_32x32x16_bf16(a, B[ks], acc, 0, 0, 0);
            }
#pragma unroll
            for (int q = 0; q < 4; ++q) {
                const int n0 = f * 32 + q * 8 + hi * 4;
                f32x4 xv = *(const f32x4*)(xR + n0);
#pragma unroll
                for (int i = 0; i < 4; ++i) {
                    float p = acc[q * 4 + i];
                    float fv = (p > 0.f) ? (p + 1.f) : __expf(p);   // elu+1
                    sdot = fmaf(fv, xv[i], sdot);
                }
            }
        }
        if (t < TSTEPS) sumF += sdot;
    }

    // ---- reduce: wave -> row pairs -> sigmoid
#pragma unroll
    for (int off = 32; off >= 1; off >>= 1) sumF += __shfl_xor(sumF, off);
    if (lane == 0) sP[wid] = sumF;
    __syncthreads();
    if (tid < ROWS_PB) {
        float F = (sP[tid * 2] + sP[tid * 2 + 1]) * (1.f / 300.f);
        out[b8 + tid] = 1.f / (1.f + __expf(-F));
    }
}

// ---------------- launch ----------------
extern "C" void kernel_launch(void* const* d_in, const int* in_sizes, int n_in,
                              void* d_out, int out_size, void* d_ws, size_t ws_size,
                              hipStream_t stream)
{
    const float* x  = (const float*)d_in[0];
    const float* W1 = (const float*)d_in[1];
    const float* b1 = (const float*)d_in[2];
    const float* W2 = (const float*)d_in[3];
    const float* b2 = (const float*)d_in[4];
    const float* W3 = (const float*)d_in[5];
    const float* b3 = (const float*)d_in[6];
    const float* U1 = (const float*)d_in[7];
    const float* c1 = (const float*)d_in[8];
    const float* U2 = (const float*)d_in[9];
    const float* c2 = (const float*)d_in[10];
    const float* U3 = (const float*)d_in[11];
    const float* c3 = (const float*)d_in[12];
    const float* U4 = (const float*)d_in[13];
    const float* c4 = (const float*)d_in[14];
    float* out = (float*)d_out;
    unsigned char* ws = (unsigned char*)d_ws;

    prep_kernel<<<128, 256, 0, stream>>>(W1, b1, W2, b2, W3, b3, U1, c1,
                                         U2, c2, U3, c3, U4, c4, ws);
    hipFuncSetAttribute((const void*)embed2,
                        hipFuncAttributeMaxDynamicSharedMemorySize, SMEM_E);
    embed2<<<64, 256, SMEM_E, stream>>>(x, ws);
    hipFuncSetAttribute((const void*)umnn_main,
                        hipFuncAttributeMaxDynamicSharedMemorySize, SMEM_M);
    umnn_main<<<BATCH / ROWS_PB, 1024, SMEM_M, stream>>>(x, ws, out);
}

// Round 8
// 160.944 us; speedup vs baseline: 1.4922x; 1.0020x over previous
//
#include <hip/hip_runtime.h>

// ---------------- types / helpers ----------------
typedef __attribute__((ext_vector_type(8))) short bf16x8;   // 8 bf16 = 4 VGPR
typedef __attribute__((ext_vector_type(4))) float f32x4;
typedef __attribute__((ext_vector_type(16))) float f32x16;
typedef int v2i __attribute__((ext_vector_type(2)));

union U4B { unsigned u[4]; bf16x8 v; };

__device__ __forceinline__ unsigned short f2bf(float f) {
    union { float f; unsigned u; } v; v.f = f;
    unsigned r = v.u + 0x7fffu + ((v.u >> 16) & 1u);   // RNE
    return (unsigned short)(r >> 16);
}
__device__ __forceinline__ float bf2f(unsigned short s) {
    union { unsigned u; float f; } v; v.u = ((unsigned)s) << 16; return v.f;
}
__device__ __forceinline__ unsigned pkbf(float a, float b) {
    unsigned r;
    asm("v_cvt_pk_bf16_f32 %0, %1, %2" : "=v"(r) : "v"(a), "v"(b));
    return r;
}
// C-frag half (regs base..base+7) -> B-frag of the next layer (verified r3-r6)
__device__ __forceinline__ bf16x8 packhalf(const f32x16& a, int base) {
    unsigned u  = pkbf(a[base + 0], a[base + 1]);
    unsigned u2 = pkbf(a[base + 2], a[base + 3]);
    unsigned v  = pkbf(a[base + 4], a[base + 5]);
    unsigned v2 = pkbf(a[base + 6], a[base + 7]);
    v2i r1 = __builtin_amdgcn_permlane32_swap(u, v, false, false);
    v2i r2 = __builtin_amdgcn_permlane32_swap(u2, v2, false, false);
    U4B b; b.u[0] = r1.x; b.u[1] = r2.x; b.u[2] = r1.y; b.u[3] = r2.y;
    return b.v;
}
__device__ __forceinline__ f32x16 zero16() {
    f32x16 v;
#pragma unroll
    for (int i = 0; i < 16; ++i) v[i] = 0.f;
    return v;
}

// ---------------- problem constants ----------------
#define BATCH   2048
#define TSTEPS  300
#define ROWS_PB 8            // batch rows per main block (16 waves)
// workspace layout (bytes)
#define WM_OFF   0           // 3 * 128*128 bf16 main weights (bias@k=100, carrier n=100)
#define G_OFF    98304       // 2048*128 bf16
#define E_OFF    622592      // 2048*128 bf16 (ends 1146880)
#define EW1_OFF  1146880     // [224][128] bf16 = 57344
#define EU1X_OFF 1204224     // [128][128] bf16 = 32768
#define EW2_OFF  1236992     // [224][256] bf16 = 114688
#define EW3_OFF  1351680     // [64][256]  bf16 = 32768
#define EU1H_OFF 1384448     // [128][128] bf16 = 32768
#define EB_OFF   1417216     // 640 f32: b1'[224] b2'[224] b3[64] c1'[128]
// main-kernel LDS (bytes) — STATIC shared so the compiler sees 110KB ->
// 1 block/CU -> 4 waves/EU -> 128-VGPR budget (dynamic LDS made it assume
// 8 waves/EU -> 64-VGPR cap -> 2MB spills, r4-r6)
#define OFF_X   98304        // 8*128 f32
#define OFF_G   102400
#define OFF_E   106496
#define OFF_P   110592       // 16 f32 wave partials
#define SMEM_M  110656
// embed-kernel LDS (bytes): weight staging 0..114688, then act + biases
#define EACT    114688       // [32][256] bf16 = 16384 (XOR-swizzled act handoff)
#define EB1     131072       // 224 f32
#define EB2     131968       // 224 f32
#define EB3     132864       // 64 f32
#define EC1     133120       // 128 f32
#define SMEM_E  133632

// ---------------- prep: ALL weight conversion, source-coalesced ----------------
__global__ __launch_bounds__(256) void prep_kernel(
    const float* __restrict__ W1, const float* __restrict__ b1,
    const float* __restrict__ W2, const float* __restrict__ b2,
    const float* __restrict__ W3, const float* __restrict__ b3,
    const float* __restrict__ U1, const float* __restrict__ c1,
    const float* __restrict__ U2, const float* __restrict__ c2,
    const float* __restrict__ U3, const float* __restrict__ c3,
    const float* __restrict__ U4, const float* __restrict__ c4,
    unsigned char* __restrict__ ws)
{
    const int NT = 128 * 256;
    const int gid = blockIdx.x * 256 + threadIdx.x;
    unsigned short* w16 = (unsigned short*)ws;

    // main weights W2',W3',W4' [n][k] 128x128 each; bias@k=100, carrier(100,100)=1
    for (int j = gid; j < 3 * 128 * 128; j += NT) {
        int m = j >> 14, r = j & 16383;
        int k = r >> 7, n = r & 127;
        float v = 0.f;
        if (m == 2) {
            if (k < 100)       v = U4[k * 128 + n];
            else if (k == 100) v = c4[n];
        } else {
            const float* U = m ? U3 : U2;
            const float* c = m ? c3 : c2;
            if (k < 100)       { if (n < 100) v = U[k * 100 + n]; }
            else if (k == 100) { if (n < 100) v = c[n]; else if (n == 100) v = 1.f; }
        }
        w16[(WM_OFF >> 1) + m * 16384 + n * 128 + k] = f2bf(v);
    }
    // W1' [224][128]
    for (int j = gid; j < 128 * 224; j += NT) {
        int k = j / 224, n = j % 224;
        float v = (n < 200) ? W1[k * 200 + n] : 0.f;
        w16[(EW1_OFF >> 1) + n * 128 + k] = f2bf(v);
    }
    // U1x [128][128]
    for (int j = gid; j < 128 * 128; j += NT) {
        int k = j >> 7, n = j & 127;
        float v = (n < 100) ? U1[k * 100 + n] : 0.f;
        w16[(EU1X_OFF >> 1) + n * 128 + k] = f2bf(v);
    }
    // U1h [128][128] (k<64 real)
    for (int j = gid; j < 128 * 128; j += NT) {
        int k = j >> 7, n = j & 127;
        float v = (k < 64 && n < 100) ? U1[(128 + k) * 100 + n] : 0.f;
        w16[(EU1H_OFF >> 1) + n * 128 + k] = f2bf(v);
    }
    // W2' [224][256]
    for (int j = gid; j < 256 * 224; j += NT) {
        int k = j / 224, n = j % 224;
        float v = (k < 200 && n < 200) ? W2[k * 200 + n] : 0.f;
        w16[(EW2_OFF >> 1) + n * 256 + k] = f2bf(v);
    }
    // W3' [64][256]
    for (int j = gid; j < 256 * 64; j += NT) {
        int k = j >> 6, n = j & 63;
        float v = (k < 200) ? W3[k * 64 + n] : 0.f;
        w16[(EW3_OFF >> 1) + n * 256 + k] = f2bf(v);
    }
    // biases (f32, padded, contiguous: b1'[224] b2'[224] b3[64] c1'[128])
    if (gid < 640) {
        int j = gid; float v;
        if (j < 224)      v = (j < 200) ? b1[j] : 0.f;
        else if (j < 448) v = (j - 224 < 200) ? b2[j - 224] : 0.f;
        else if (j < 512) v = b3[j - 448];
        else              v = (j - 512 < 100) ? c1[j - 512] : 0.f;
        ((float*)(ws + EB_OFF))[j] = v;
    }
}

// ---------------- embed: f-split MFMA pipeline, 64 blocks x 32 rows ----------
__device__ __forceinline__ void act_store(char* act, int l31, int f, int hi,
                                          const f32x16& a) {
#pragma unroll
    for (int r = 0; r < 16; r += 2) {
        int n = 32 * f + (r & 3) + 8 * (r >> 2) + 4 * hi;
        unsigned u = pkbf(fmaxf(a[r], 0.f), fmaxf(a[r + 1], 0.f));   // relu fused
        *(unsigned*)(act + l31 * 512 + ((n * 2) ^ ((l31 & 7) << 4))) = u;
    }
}
__device__ __forceinline__ bf16x8 act_read(const char* act, int l31, int ks, int hi) {
    return *(const bf16x8*)(act + l31 * 512 + ((ks * 32 + hi * 16) ^ ((l31 & 7) << 4)));
}

__global__ __launch_bounds__(256) void embed2(
    const float* __restrict__ x, unsigned char* __restrict__ ws)
{
    __shared__ __align__(16) char sm[SMEM_E];
    char* act = sm + EACT;
    const int tid = threadIdx.x;
    const int lane = tid & 63, wid = tid >> 6;
    const int l31 = lane & 31, hi = lane >> 5;
    const int brow = blockIdx.x * 32 + l31;   // grid = 64
    const int sw8 = (l31 & 15) << 4;    // 256B-row weight swizzle
    const int sw9 = (l31 & 31) << 4;    // 512B-row weight swizzle

    // biases -> LDS (contiguous 640 f32; region persists)
    for (int i = tid; i < 640; i += 256)
        ((float*)(sm + EB1))[i] = ((const float*)(ws + EB_OFF))[i];

    // ---- stage A: W1' [224][128] + U1x [128][128]
    {
        const uint4* s1 = (const uint4*)(ws + EW1_OFF);
        for (int ci = tid; ci < 3584; ci += 256) {
            int n = ci >> 4, part = ci & 15;
            *(uint4*)(sm + n * 256 + ((part * 16) ^ ((n & 15) << 4))) = s1[ci];
        }
        const uint4* s2 = (const uint4*)(ws + EU1X_OFF);
        for (int ci = tid; ci < 2048; ci += 256) {
            int n = ci >> 4, part = ci & 15;
            *(uint4*)(sm + 57344 + n * 256 + ((part * 16) ^ ((n & 15) << 4))) = s2[ci];
        }
    }

    // x B-frags (all waves: same 32 rows)
    bf16x8 Bx[8];
    {
        const float* xr = x + brow * 128;
#pragma unroll
        for (int ks = 0; ks < 8; ++ks) {
            const int k0 = ks * 16 + hi * 8;
            f32x4 a = *(const f32x4*)(xr + k0);
            f32x4 b = *(const f32x4*)(xr + k0 + 4);
            U4B u;
            u.u[0] = pkbf(a[0], a[1]); u.u[1] = pkbf(a[2], a[3]);
            u.u[2] = pkbf(b[0], b[1]); u.u[3] = pkbf(b[2], b[3]);
            Bx[ks] = u.v;
        }
    }
    __syncthreads();

    unsigned short* g16 = (unsigned short*)(ws + G_OFF);
    unsigned short* e16 = (unsigned short*)(ws + E_OFF);

    // ---- g = x @ U1x (frag = wid) -> global, no bias/relu
    {
        f32x16 ag = zero16();
#pragma unroll
        for (int ks = 0; ks < 8; ++ks) {
            bf16x8 a = *(const bf16x8*)(sm + 57344 + (32 * wid + l31) * 256 + ((ks * 32 + hi * 16) ^ sw8));
            ag = __builtin_amdgcn_mfma_f32_32x32x16_bf16(a, Bx[ks], ag, 0, 0, 0);
        }
#pragma unroll
        for (int r = 0; r < 16; r += 2) {
            int n = 32 * wid + (r & 3) + 8 * (r >> 2) + 4 * hi;
            *(unsigned*)(g16 + brow * 128 + n) = pkbf(ag[r], ag[r + 1]);
        }
    }

    // ---- layer 1: frags {wid, wid+4} of relu(x@W1'+b1) -> act
    for (int f = wid; f < 7; f += 4) {
        f32x16 acc;
#pragma unroll
        for (int r = 0; r < 16; ++r)
            acc[r] = ((float*)(sm + EB1))[32 * f + (r & 3) + 8 * (r >> 2) + 4 * hi];
#pragma unroll
        for (int ks = 0; ks < 8; ++ks) {
            bf16x8 a = *(const bf16x8*)(sm + (32 * f + l31) * 256 + ((ks * 32 + hi * 16) ^ sw8));
            acc = __builtin_amdgcn_mfma_f32_32x32x16_bf16(a, Bx[ks], acc, 0, 0, 0);
        }
        act_store(act, l31, f, hi, acc);
    }
    __syncthreads();

    // ---- read Bh (13 frags) ; stage B: W2' [224][256] (disjoint LDS regions)
    bf16x8 Bh[13];
#pragma unroll
    for (int ks = 0; ks < 13; ++ks) Bh[ks] = act_read(act, l31, ks, hi);
    __syncthreads();   // all reads done before staging overwrites
    {
        const uint4* s3 = (const uint4*)(ws + EW2_OFF);
        for (int ci = tid; ci < 7168; ci += 256) {
            int n = ci >> 5, part = ci & 31;
            *(uint4*)(sm + n * 512 + ((part * 16) ^ ((n & 31) << 4))) = s3[ci];
        }
    }
    __syncthreads();

    // ---- layer 2: frags {wid, wid+4} of relu(h1@W2'+b2) -> act
    for (int f = wid; f < 7; f += 4) {
        f32x16 acc;
#pragma unroll
        for (int r = 0; r < 16; ++r)
            acc[r] = ((float*)(sm + EB2))[32 * f + (r & 3) + 8 * (r >> 2) + 4 * hi];
#pragma unroll
        for (int ks = 0; ks < 13; ++ks) {
            bf16x8 a = *(const bf16x8*)(sm + (32 * f + l31) * 512 + ((ks * 32 + hi * 16) ^ sw9));
            acc = __builtin_amdgcn_mfma_f32_32x32x16_bf16(a, Bh[ks], acc, 0, 0, 0);
        }
        act_store(act, l31, f, hi, acc);
    }
    __syncthreads();

    // ---- read Bh2 (13 frags) ; stage C: W3' [64][256] + U1h [128][128]
    bf16x8 Bh2[13];
#pragma unroll
    for (int ks = 0; ks < 13; ++ks) Bh2[ks] = act_read(act, l31, ks, hi);
    __syncthreads();
    {
        const uint4* s4 = (const uint4*)(ws + EW3_OFF);
        for (int ci = tid; ci < 2048; ci += 256) {
            int n = ci >> 5, part = ci & 31;
            *(uint4*)(sm + n * 512 + ((part * 16) ^ ((n & 31) << 4))) = s4[ci];
        }
        const uint4* s5 = (const uint4*)(ws + EU1H_OFF);
        for (int ci = tid; ci < 2048; ci += 256) {
            int n = ci >> 4, part = ci & 15;
            *(uint4*)(sm + 32768 + n * 256 + ((part * 16) ^ ((n & 15) << 4))) = s5[ci];
        }
    }
    __syncthreads();

    // ---- layer 3: frags {wid} < 2 of relu(h2@W3'+b3) -> act (n<64)
    for (int f = wid; f < 2; f += 4) {
        f32x16 acc;
#pragma unroll
        for (int r = 0; r < 16; ++r)
            acc[r] = ((float*)(sm + EB3))[32 * f + (r & 3) + 8 * (r >> 2) + 4 * hi];
#pragma unroll
        for (int ks = 0; ks < 13; ++ks) {
            bf16x8 a = *(const bf16x8*)(sm + (32 * f + l31) * 512 + ((ks * 32 + hi * 16) ^ sw9));
            acc = __builtin_amdgcn_mfma_f32_32x32x16_bf16(a, Bh2[ks], acc, 0, 0, 0);
        }
        act_store(act, l31, f, hi, acc);
    }
    __syncthreads();

    // ---- e = h3 @ U1h + c1 (frag = wid) -> global ; e[100]=1 carrier
    {
        f32x16 ae;
#pragma unroll
        for (int r = 0; r < 16; ++r)
            ae[r] = ((float*)(sm + EC1))[32 * wid + (r & 3) + 8 * (r >> 2) + 4 * hi];
        bf16x8 B4[4];
#pragma unroll
        for (int ks = 0; ks < 4; ++ks) B4[ks] = act_read(act, l31, ks, hi);
#pragma unroll
        for (int ks = 0; ks < 4; ++ks) {
            bf16x8 a = *(const bf16x8*)(sm + 32768 + (32 * wid + l31) * 256 + ((ks * 32 + hi * 16) ^ sw8));
            ae = __builtin_amdgcn_mfma_f32_32x32x16_bf16(a, B4[ks], ae, 0, 0, 0);
        }
#pragma unroll
        for (int r = 0; r < 16; r += 2) {
            int n = 32 * wid + (r & 3) + 8 * (r >> 2) + 4 * hi;
            float v0 = ae[r], v1 = ae[r + 1];
            if (wid == 3 && hi == 1 && r == 0) v0 = 1.f;   // n==100 carrier
            *(unsigned*)(e16 + brow * 128 + n) = pkbf(v0, v1);
        }
    }
}

// ---------------- main fused UMNN kernel (16 waves, barrier-free pipelines) ----
__global__ __launch_bounds__(1024)
__attribute__((amdgpu_waves_per_eu(4, 4))) void umnn_main(
    const float* __restrict__ x,
    const unsigned char* __restrict__ ws, float* __restrict__ out)
{
    __shared__ __align__(16) char sm[SMEM_M];   // STATIC: see note at SMEM_M
    float* sX = (float*)(sm + OFF_X);   // [8][128]
    float* sG = (float*)(sm + OFF_G);
    float* sE = (float*)(sm + OFF_E);
    float* sP = (float*)(sm + OFF_P);
    const int tid = threadIdx.x;
    const int lane = tid & 63, wid = tid >> 6;
    const int l31 = lane & 31, hi = lane >> 5;
    const int b8 = blockIdx.x * ROWS_PB;   // grid = 256

    // ---- stage weights (swizzled) + per-row vectors
    {
        const uint4* src = (const uint4*)(ws + WM_OFF);   // 6144 x 16B
        for (int ci = tid; ci < 6144; ci += 1024) {
            int m = ci >> 11, wi = ci & 2047, n = wi >> 4, part = wi & 15;
            uint4 v = src[ci];
            *(uint4*)(sm + m * 32768 + n * 256 + ((part * 16) ^ ((n & 15) << 4))) = v;
        }
        const unsigned short* g16 = (const unsigned short*)(ws + G_OFF);
        const unsigned short* e16 = (const unsigned short*)(ws + E_OFF);
        {
            int r = tid >> 7, d = tid & 127;   // 1024 threads = 8*128
            sX[tid] = x[(b8 + r) * 128 + d];
            sG[tid] = bf2f(g16[(b8 + r) * 128 + d]);
            sE[tid] = bf2f(e16[(b8 + r) * 128 + d]);
        }
    }
    __syncthreads();

    const int row = wid >> 1, half = wid & 1;
    const float* gR = sG + row * 128;
    const float* eR = sE + row * 128;
    const float* xR = sX + row * 128;
    const int sw = (l31 & 15) << 4;
    const char* wB2 = sm;
    const char* wB3 = sm + 32768;
    const char* wB4 = sm + 65536;

    float sumF = 0.f;

#pragma unroll 1
    for (int s = 0; s < 5; ++s) {
        const int t = half * 160 + s * 32 + l31;
        const float tt = ((float)t + 0.5f) * (1.f / 300.f);

        // ---- genA: B[ks] = bf16(relu(tt*g + e)), ks 0..6 (k 112..127 zero)
        bf16x8 B[7];
#pragma unroll
        for (int ks = 0; ks < 7; ++ks) {
            const int k0 = ks * 16 + hi * 8;
            f32x4 g0 = *(const f32x4*)(gR + k0);
            f32x4 g1 = *(const f32x4*)(gR + k0 + 4);
            f32x4 e0 = *(const f32x4*)(eR + k0);
            f32x4 e1 = *(const f32x4*)(eR + k0 + 4);
            float a0 = fmaxf(fmaf(tt, g0[0], e0[0]), 0.f);
            float a1 = fmaxf(fmaf(tt, g0[1], e0[1]), 0.f);
            float a2 = fmaxf(fmaf(tt, g0[2], e0[2]), 0.f);
            float a3 = fmaxf(fmaf(tt, g0[3], e0[3]), 0.f);
            float a4 = fmaxf(fmaf(tt, g1[0], e1[0]), 0.f);
            float a5 = fmaxf(fmaf(tt, g1[1], e1[1]), 0.f);
            float a6 = fmaxf(fmaf(tt, g1[2], e1[2]), 0.f);
            float a7 = fmaxf(fmaf(tt, g1[3], e1[3]), 0.f);
            U4B u;
            u.u[0] = pkbf(a0, a1); u.u[1] = pkbf(a2, a3);
            u.u[2] = pkbf(a4, a5); u.u[3] = pkbf(a6, a7);
            B[ks] = u.v;
        }

        // ---- layers 2 and 3: GEMM + relu + in-register repack
#pragma unroll
        for (int L = 0; L < 2; ++L) {
            const char* wb = (L == 0) ? wB2 : wB3;
            f32x16 acc[4];
#pragma unroll
            for (int f = 0; f < 4; ++f) acc[f] = zero16();
#pragma unroll
            for (int ks = 0; ks < 7; ++ks) {
                const int ko = ks * 32 + hi * 16;
#pragma unroll
                for (int f = 0; f < 4; ++f) {
                    bf16x8 a = *(const bf16x8*)(wb + (32 * f + l31) * 256 + (ko ^ sw));
                    acc[f] = __builtin_amdgcn_mfma_f32_32x32x16_bf16(a, B[ks], acc[f], 0, 0, 0);
                }
            }
#pragma unroll
            for (int f = 0; f < 4; ++f) {
#pragma unroll
                for (int r = 0; r < 16; ++r) acc[f][r] = fmaxf(acc[f][r], 0.f);
                B[2 * f] = packhalf(acc[f], 0);
                if (f < 3) B[2 * f + 1] = packhalf(acc[f], 8);
            }
        }

        // ---- layer 4 + fused elu(p)+1 dot x
        float sdot = 0.f;
#pragma unroll
        for (int f = 0; f < 4; ++f) {
            f32x16 acc = zero16();
#pragma unroll
            for (int ks = 0; ks < 7; ++ks) {
                const int ko = ks * 32 + hi * 16;
                bf16x8 a = *(const bf16x8*)(wB4 + (32 * f + l31) * 256 + (ko ^ sw));
                acc = __builtin_amdgcn_mfma_f32_32x32x16_bf16(a, B[ks], acc, 0, 0, 0);
            }
#pragma unroll
            for (int q = 0; q < 4; ++q) {
                const int n0 = f * 32 + q * 8 + hi * 4;
                f32x4 xv = *(const f32x4*)(xR + n0);
#pragma unroll
                for (int i = 0; i < 4; ++i) {
                    float p = acc[q * 4 + i];
                    float fv = (p > 0.f) ? (p + 1.f) : __expf(p);   // elu+1
                    sdot = fmaf(fv, xv[i], sdot);
                }
            }
        }
        if (t < TSTEPS) sumF += sdot;
    }

    // ---- reduce: wave -> row pairs -> sigmoid
#pragma unroll
    for (int off = 32; off >= 1; off >>= 1) sumF += __shfl_xor(sumF, off);
    if (lane == 0) sP[wid] = sumF;
    __syncthreads();
    if (tid < ROWS_PB) {
        float F = (sP[tid * 2] + sP[tid * 2 + 1]) * (1.f / 300.f);
        out[b8 + tid] = 1.f / (1.f + __expf(-F));
    }
}

// ---------------- launch ----------------
extern "C" void kernel_launch(void* const* d_in, const int* in_sizes, int n_in,
                              void* d_out, int out_size, void* d_ws, size_t ws_size,
                              hipStream_t stream)
{
    const float* x  = (const float*)d_in[0];
    const float* W1 = (const float*)d_in[1];
    const float* b1 = (const float*)d_in[2];
    const float* W2 = (const float*)d_in[3];
    const float* b2 = (const float*)d_in[4];
    const float* W3 = (const float*)d_in[5];
    const float* b3 = (const float*)d_in[6];
    const float* U1 = (const float*)d_in[7];
    const float* c1 = (const float*)d_in[8];
    const float* U2 = (const float*)d_in[9];
    const float* c2 = (const float*)d_in[10];
    const float* U3 = (const float*)d_in[11];
    const float* c3 = (const float*)d_in[12];
    const float* U4 = (const float*)d_in[13];
    const float* c4 = (const float*)d_in[14];
    float* out = (float*)d_out;
    unsigned char* ws = (unsigned char*)d_ws;

    prep_kernel<<<128, 256, 0, stream>>>(W1, b1, W2, b2, W3, b3, U1, c1,
                                         U2, c2, U3, c3, U4, c4, ws);
    embed2<<<64, 256, 0, stream>>>(x, ws);
    umnn_main<<<BATCH / ROWS_PB, 1024, 0, stream>>>(x, ws, out);
}